// Round 8
// baseline (825.944 us; speedup 1.0000x reference)
//
#include <hip/hip_runtime.h>
#include <hip/hip_bf16.h>
#include <hip/hip_fp16.h>

#define NG 512  // NUM_GRAPHS
#define EPS_BN 1e-5f

__device__ __forceinline__ float4 f4add(float4 a, float4 b) {
    a.x += b.x; a.y += b.y; a.z += b.z; a.w += b.w; return a;
}
__device__ __forceinline__ float4 f4fma(float s, float4 b, float4 a) {
    a.x = fmaf(s, b.x, a.x); a.y = fmaf(s, b.y, a.y);
    a.z = fmaf(s, b.z, a.z); a.w = fmaf(s, b.w, a.w); return a;
}
__device__ __forceinline__ float4 f4max(float4 a, float4 b) {
    a.x = fmaxf(a.x, b.x); a.y = fmaxf(a.y, b.y);
    a.z = fmaxf(a.z, b.z); a.w = fmaxf(a.w, b.w); return a;
}
__device__ __forceinline__ void bnparam(float sm, float sq, float ga, float bt,
                                        float invN, float& sc, float& sh) {
    float m = sm * invN;
    float var = fmaf(-m, m, sq * invN);
    sc = ga * rsqrtf(var + EPS_BN);
    sh = fmaf(-m, sc, bt);
}
// monotone float<->int ordering keys (for atomicMax over signed ints)
__device__ __forceinline__ int enckey(float f) {
    int u = __float_as_int(f);
    return u >= 0 ? u : (u ^ 0x7fffffff);
}
__device__ __forceinline__ float deckey(int k) {
    return __int_as_float(k >= 0 ? k : (k ^ 0x7fffffff));
}
// decode 8 fp16 (raw float4) -> bn+relu -> fma into acc[8]
__device__ __forceinline__ void fma_h8(float4 raw, float w, const float* sc,
                                       const float* sh, float* acc) {
    const __half2* hp = reinterpret_cast<const __half2*>(&raw);
#pragma unroll
    for (int i = 0; i < 4; ++i) {
        float2 t = __half22float2(hp[i]);
        acc[2 * i]     = fmaf(w, fmaxf(fmaf(sc[2 * i],     t.x, sh[2 * i]),     0.f), acc[2 * i]);
        acc[2 * i + 1] = fmaf(w, fmaxf(fmaf(sc[2 * i + 1], t.y, sh[2 * i + 1]), 0.f), acc[2 * i + 1]);
    }
}

// ---------------- degree / normalization ----------------

__global__ void k_count(const int* __restrict__ dst, int* __restrict__ cnt, int E) {
    int i = blockIdx.x * blockDim.x + threadIdx.x;
    if (i < E) atomicAdd(&cnt[dst[i]], 1);
}

__global__ void k_dinv(const int* __restrict__ cnt, float* __restrict__ dinv, int N) {
    int i = blockIdx.x * blockDim.x + threadIdx.x;
    if (i < N) dinv[i] = rsqrtf((float)cnt[i] + 1.0f);  // +1 self-loop
}

// ---------------- exclusive prefix-sum over cnt -> rowptr ----------------

#define SCAN_T 256
#define SCAN_I 4  // 1024 elements per block

__global__ void k_scan1(const int* __restrict__ in, int* __restrict__ out,
                        int* __restrict__ bsum, int N) {
    __shared__ int lds[SCAN_T];
    int t = threadIdx.x;
    int base = blockIdx.x * (SCAN_T * SCAN_I) + t * SCAN_I;
    int v[SCAN_I];
    int sum = 0;
#pragma unroll
    for (int i = 0; i < SCAN_I; ++i) {
        int idx = base + i;
        v[i] = (idx < N) ? in[idx] : 0;
        sum += v[i];
    }
    lds[t] = sum;
    __syncthreads();
    for (int o = 1; o < SCAN_T; o <<= 1) {
        int a = (t >= o) ? lds[t - o] : 0;
        __syncthreads();
        lds[t] += a;
        __syncthreads();
    }
    int run = lds[t] - sum;
#pragma unroll
    for (int i = 0; i < SCAN_I; ++i) {
        int idx = base + i;
        if (idx < N) out[idx] = run;
        run += v[i];
    }
    if (t == SCAN_T - 1) bsum[blockIdx.x] = lds[SCAN_T - 1];
}

__global__ void k_scan2(int* __restrict__ bs, int nb) {
    __shared__ int lds[SCAN_T];
    int t = threadIdx.x;
    int runbase = 0;
    for (int start = 0; start < nb; start += SCAN_T) {
        int idx = start + t;
        int v = (idx < nb) ? bs[idx] : 0;
        lds[t] = v;
        __syncthreads();
        for (int o = 1; o < SCAN_T; o <<= 1) {
            int a = (t >= o) ? lds[t - o] : 0;
            __syncthreads();
            lds[t] += a;
            __syncthreads();
        }
        if (idx < nb) bs[idx] = runbase + lds[t] - v;
        int tot = lds[SCAN_T - 1];
        __syncthreads();
        runbase += tot;
    }
}

__global__ void k_scan3(int* __restrict__ out, const int* __restrict__ bs, int N) {
    int add = bs[blockIdx.x];
    int base = blockIdx.x * (SCAN_T * SCAN_I) + threadIdx.x * SCAN_I;
#pragma unroll
    for (int i = 0; i < SCAN_I; ++i) {
        int idx = base + i;
        if (idx < N) out[idx] += add;
    }
}

// ---------------- bucket edges by dst (CSR), pre-bake per-edge weight dinv[src] ----------------

__global__ void k_bucket(const int* __restrict__ src, const int* __restrict__ dst,
                         const float* __restrict__ dinv, const int* __restrict__ rowptr,
                         int* __restrict__ fill, int* __restrict__ esrc,
                         float* __restrict__ ewt, int E) {
    int e = blockIdx.x * blockDim.x + threadIdx.x;
    if (e >= E) return;
    int d = dst[e], s = src[e];
    int pos = rowptr[d] + atomicAdd(&fill[d], 1);
    esrc[pos] = s;
    ewt[pos] = dinv[s];
}

// ---------------- fused layer 1: gather raw x (C=6) + mm 6->32 + stats; H1 stored fp16 ----------------

template <int COUT>
__global__ __launch_bounds__(256) void k_layer1(
    const int* __restrict__ rowptr, const int* __restrict__ cnt,
    const int* __restrict__ esrc, const float* __restrict__ ewt,
    const float* __restrict__ dinv, const float* __restrict__ x,
    const float* __restrict__ W, __half* __restrict__ hout,
    float* __restrict__ sums, float* __restrict__ sumsq, int N) {
    constexpr int NPB = 256;
    constexpr int CG = COUT / 4;   // 8
    constexpr int RPB = 256 / CG;  // 32
    __shared__ float4 inT4[NPB * 6 / 4];
    float* inT = (float*)inT4;
    __shared__ float4 wT[6 * CG];
    __shared__ float4 red[256];
    int t = threadIdx.x;
    const float4* W4 = (const float4*)W;
    for (int i = t; i < 6 * CG; i += 256) wT[i] = W4[i];
    int base = blockIdx.x * NPB;
    int n = base + t;
    if (n < N) {
        const float2* x2 = (const float2*)x;
        int beg = rowptr[n], end = beg + cnt[n];
        float di = dinv[n];
        size_t b3 = (size_t)n * 3;
        float2 p0 = x2[b3], p1 = x2[b3 + 1], p2 = x2[b3 + 2];
        float a0 = di * p0.x, a1 = di * p0.y, a2 = di * p1.x;
        float a3 = di * p1.y, a4 = di * p2.x, a5 = di * p2.y;
        for (int e = beg; e < end; ++e) {
            int s = esrc[e];
            float w = ewt[e];
            size_t s3 = (size_t)s * 3;
            float2 q0 = x2[s3], q1 = x2[s3 + 1], q2 = x2[s3 + 2];
            a0 = fmaf(w, q0.x, a0); a1 = fmaf(w, q0.y, a1);
            a2 = fmaf(w, q1.x, a2); a3 = fmaf(w, q1.y, a3);
            a4 = fmaf(w, q2.x, a4); a5 = fmaf(w, q2.y, a5);
        }
        int o = t * 6;
        inT[o + 0] = di * a0; inT[o + 1] = di * a1; inT[o + 2] = di * a2;
        inT[o + 3] = di * a3; inT[o + 4] = di * a4; inT[o + 5] = di * a5;
    }
    __syncthreads();
    int gi = t % CG, r0 = t / CG, c0 = gi * 4;
    int nrows = min(NPB, N - base);
    float4 s = {0, 0, 0, 0}, s2 = {0, 0, 0, 0};
    for (int r = r0; r < nrows; r += RPB) {
        const float* row = inT + r * 6;
        float4 acc = {0, 0, 0, 0};
#pragma unroll
        for (int k = 0; k < 6; ++k) acc = f4fma(row[k], wT[k * CG + gi], acc);
        union { __half2 h2[2]; uint2 u; } cv;
        cv.h2[0] = __float22half2_rn(make_float2(acc.x, acc.y));
        cv.h2[1] = __float22half2_rn(make_float2(acc.z, acc.w));
        reinterpret_cast<uint2*>(hout)[(size_t)(base + r) * CG + gi] = cv.u;
        s = f4add(s, acc);
        s2.x = fmaf(acc.x, acc.x, s2.x);
        s2.y = fmaf(acc.y, acc.y, s2.y);
        s2.z = fmaf(acc.z, acc.z, s2.z);
        s2.w = fmaf(acc.w, acc.w, s2.w);
    }
    red[t] = s;
    for (int hh = RPB / 2; hh > 0; hh >>= 1) {
        __syncthreads();
        if (r0 < hh) red[t] = f4add(red[t], red[t + hh * CG]);
    }
    if (r0 == 0) {
        float4 a = red[t];
        atomicAdd(&sums[c0 + 0], a.x); atomicAdd(&sums[c0 + 1], a.y);
        atomicAdd(&sums[c0 + 2], a.z); atomicAdd(&sums[c0 + 3], a.w);
    }
    __syncthreads();
    red[t] = s2;
    for (int hh = RPB / 2; hh > 0; hh >>= 1) {
        __syncthreads();
        if (r0 < hh) red[t] = f4add(red[t], red[t + hh * CG]);
    }
    if (r0 == 0) {
        float4 b = red[t];
        atomicAdd(&sumsq[c0 + 0], b.x); atomicAdd(&sumsq[c0 + 1], b.y);
        atomicAdd(&sumsq[c0 + 2], b.z); atomicAdd(&sumsq[c0 + 3], b.w);
    }
}

// ---------------- fused layer: fp16 gather(+BN_prev+ReLU) + mm + stats ----------------
// SEGMAX=false: write hout (fp16). SEGMAX=true: no hout; per-graph raw max -> pool
// (valid because BN (gamma=1>0) and ReLU are non-decreasing; BN applied post-pool).

template <int CIN, int COUT, int NPB, bool SEGMAX>
__global__ __launch_bounds__(256, 6) void k_layerF(
    const int* __restrict__ rowptr, const int* __restrict__ cnt,
    const int* __restrict__ esrc, const float* __restrict__ ewt,
    const float* __restrict__ dinv, const __half* __restrict__ hin,
    const float* __restrict__ sums_in, const float* __restrict__ sumsq_in,
    const float* __restrict__ gam, const float* __restrict__ bet,
    const float* __restrict__ W, __half* __restrict__ hout,
    float* __restrict__ sums_out, float* __restrict__ sumsq_out,
    const int* __restrict__ batch, int* __restrict__ pool,
    int N, float invN) {
    constexpr int TPN = CIN / 8;      // threads per node (each covers 8 channels, 16B fp16)
    constexpr int PAD = CIN / 4 + 1;  // LDS row stride in float4 (fp32)
    constexpr int ITER1 = NPB * TPN / 256;
    constexpr int NPI = 256 / TPN;
    constexpr int CG = COUT / 4;
    constexpr int RPB = 256 / CG;
    __shared__ float4 inT4[NPB * PAD];
    __shared__ float4 red[256];
    int t = threadIdx.x;
    int base = blockIdx.x * NPB;
    // ---- phase 1: fp16 gather with BN_prev+ReLU on decoded values ----
    {
        int c8 = t % TPN;
        float sc[8], sh[8];
        {
            const float4* sm4 = (const float4*)sums_in;
            const float4* sq4 = (const float4*)sumsq_in;
            const float4* ga4 = (const float4*)gam;
            const float4* bt4 = (const float4*)bet;
#pragma unroll
            for (int q = 0; q < 2; ++q) {
                float4 sm = sm4[c8 * 2 + q], sq = sq4[c8 * 2 + q];
                float4 ga = ga4[c8 * 2 + q], bt = bt4[c8 * 2 + q];
                bnparam(sm.x, sq.x, ga.x, bt.x, invN, sc[4 * q + 0], sh[4 * q + 0]);
                bnparam(sm.y, sq.y, ga.y, bt.y, invN, sc[4 * q + 1], sh[4 * q + 1]);
                bnparam(sm.z, sq.z, ga.z, bt.z, invN, sc[4 * q + 2], sh[4 * q + 2]);
                bnparam(sm.w, sq.w, ga.w, bt.w, invN, sc[4 * q + 3], sh[4 * q + 3]);
            }
        }
        const float4* h4 = reinterpret_cast<const float4*>(hin);  // row = TPN float4s
#pragma unroll
        for (int it = 0; it < ITER1; ++it) {
            int nl = it * NPI + t / TPN;
            int n = base + nl;
            if (n < N) {
                int beg = rowptr[n], end = beg + cnt[n];
                float di = dinv[n];
                float acc[8] = {0, 0, 0, 0, 0, 0, 0, 0};
                fma_h8(h4[(size_t)n * TPN + c8], di, sc, sh, acc);  // self-loop
                int e = beg;
                for (; e + 3 < end; e += 4) {
                    int s0 = esrc[e], s1 = esrc[e + 1], s2_ = esrc[e + 2], s3_ = esrc[e + 3];
                    float w0 = ewt[e], w1 = ewt[e + 1], w2 = ewt[e + 2], w3 = ewt[e + 3];
                    float4 v0 = h4[(size_t)s0 * TPN + c8];
                    float4 v1 = h4[(size_t)s1 * TPN + c8];
                    float4 v2 = h4[(size_t)s2_ * TPN + c8];
                    float4 v3 = h4[(size_t)s3_ * TPN + c8];
                    fma_h8(v0, w0, sc, sh, acc);
                    fma_h8(v1, w1, sc, sh, acc);
                    fma_h8(v2, w2, sc, sh, acc);
                    fma_h8(v3, w3, sc, sh, acc);
                }
                for (; e < end; ++e)
                    fma_h8(h4[(size_t)esrc[e] * TPN + c8], ewt[e], sc, sh, acc);
                inT4[nl * PAD + 2 * c8] =
                    make_float4(di * acc[0], di * acc[1], di * acc[2], di * acc[3]);
                inT4[nl * PAD + 2 * c8 + 1] =
                    make_float4(di * acc[4], di * acc[5], di * acc[6], di * acc[7]);
            }
        }
    }
    __syncthreads();
    // ---- phase 2: mm from LDS (W from global), stats, and store/segmax ----
    const float4* W4 = (const float4*)W;
    int gi = t % CG, r0 = t / CG, c0 = gi * 4;
    int nrows = min(NPB, N - base);
    float4 s = {0, 0, 0, 0}, s2 = {0, 0, 0, 0};
    int curb = -1;
    float4 mx = {0, 0, 0, 0};
    for (int r = r0; r < nrows; r += RPB) {
        const float* row = (const float*)(inT4 + r * PAD);
        float4 acc = {0, 0, 0, 0};
#pragma unroll 8
        for (int k = 0; k < CIN; ++k) acc = f4fma(row[k], W4[k * CG + gi], acc);
        if constexpr (SEGMAX) {
            int b = batch[base + r];
            if (b != curb) {
                if (curb >= 0) {
                    int* p = pool + (curb << 7) + c0;
                    atomicMax(p + 0, enckey(mx.x)); atomicMax(p + 1, enckey(mx.y));
                    atomicMax(p + 2, enckey(mx.z)); atomicMax(p + 3, enckey(mx.w));
                }
                curb = b; mx = acc;
            } else {
                mx = f4max(mx, acc);
            }
        } else {
            union { __half2 h2[2]; uint2 u; } cv;
            cv.h2[0] = __float22half2_rn(make_float2(acc.x, acc.y));
            cv.h2[1] = __float22half2_rn(make_float2(acc.z, acc.w));
            reinterpret_cast<uint2*>(hout)[(size_t)(base + r) * CG + gi] = cv.u;
        }
        s = f4add(s, acc);
        s2.x = fmaf(acc.x, acc.x, s2.x);
        s2.y = fmaf(acc.y, acc.y, s2.y);
        s2.z = fmaf(acc.z, acc.z, s2.z);
        s2.w = fmaf(acc.w, acc.w, s2.w);
    }
    if constexpr (SEGMAX) {
        if (curb >= 0) {
            int* p = pool + (curb << 7) + c0;
            atomicMax(p + 0, enckey(mx.x)); atomicMax(p + 1, enckey(mx.y));
            atomicMax(p + 2, enckey(mx.z)); atomicMax(p + 3, enckey(mx.w));
        }
    }
    red[t] = s;
    for (int hh = RPB / 2; hh > 0; hh >>= 1) {
        __syncthreads();
        if (r0 < hh) red[t] = f4add(red[t], red[t + hh * CG]);
    }
    if (r0 == 0) {
        float4 a = red[t];
        atomicAdd(&sums_out[c0 + 0], a.x); atomicAdd(&sums_out[c0 + 1], a.y);
        atomicAdd(&sums_out[c0 + 2], a.z); atomicAdd(&sums_out[c0 + 3], a.w);
    }
    __syncthreads();
    red[t] = s2;
    for (int hh = RPB / 2; hh > 0; hh >>= 1) {
        __syncthreads();
        if (r0 < hh) red[t] = f4add(red[t], red[t + hh * CG]);
    }
    if (r0 == 0) {
        float4 b = red[t];
        atomicAdd(&sumsq_out[c0 + 0], b.x); atomicAdd(&sumsq_out[c0 + 1], b.y);
        atomicAdd(&sumsq_out[c0 + 2], b.z); atomicAdd(&sumsq_out[c0 + 3], b.w);
    }
}

// ---------------- head FC1: decode pool keys + BN3 + ReLU, mm 128->128, stats4 ----------------

__global__ __launch_bounds__(256) void k_mm_pool(
    const int* __restrict__ pool, const float* __restrict__ W,
    const float* __restrict__ sums3, const float* __restrict__ sumsq3,
    const float* __restrict__ g3, const float* __restrict__ be3,
    float* __restrict__ out, float* __restrict__ sums4,
    float* __restrict__ sumsq4, float invN) {
    constexpr int CIN = 128, COUT = 128, ROWS = 64;
    constexpr int CG = COUT / 4;   // 32
    constexpr int RPB = 256 / CG;  // 8
    __shared__ float4 inT4[ROWS * CIN / 4];
    __shared__ float scA[CIN];
    __shared__ float shA[CIN];
    __shared__ float4 red[256];
    int t = threadIdx.x;
    if (t < CIN) bnparam(sums3[t], sumsq3[t], g3[t], be3[t], invN, scA[t], shA[t]);
    __syncthreads();
    int base = blockIdx.x * ROWS;  // NG rows total; grid sized so base+ROWS <= NG
    {
        const int4* p4 = reinterpret_cast<const int4*>(pool) + (size_t)base * (CIN / 4);
        for (int i = t; i < ROWS * (CIN / 4); i += 256) {
            int4 k = p4[i];
            int c = (i % (CIN / 4)) * 4;
            float4 v;
            v.x = fmaxf(fmaf(scA[c + 0], deckey(k.x), shA[c + 0]), 0.f);
            v.y = fmaxf(fmaf(scA[c + 1], deckey(k.y), shA[c + 1]), 0.f);
            v.z = fmaxf(fmaf(scA[c + 2], deckey(k.z), shA[c + 2]), 0.f);
            v.w = fmaxf(fmaf(scA[c + 3], deckey(k.w), shA[c + 3]), 0.f);
            inT4[i] = v;
        }
    }
    __syncthreads();
    const float4* W4 = reinterpret_cast<const float4*>(W);
    int gi = t % CG, r0 = t / CG, c0 = gi * 4;
    float4 s = {0, 0, 0, 0}, s2 = {0, 0, 0, 0};
    for (int r = r0; r < ROWS; r += RPB) {
        const float* row = (const float*)(inT4 + r * (CIN / 4));
        float4 acc = {0, 0, 0, 0};
#pragma unroll 8
        for (int k = 0; k < CIN; ++k) acc = f4fma(row[k], W4[k * CG + gi], acc);
        reinterpret_cast<float4*>(out + (size_t)(base + r) * COUT)[gi] = acc;
        s = f4add(s, acc);
        s2.x = fmaf(acc.x, acc.x, s2.x);
        s2.y = fmaf(acc.y, acc.y, s2.y);
        s2.z = fmaf(acc.z, acc.z, s2.z);
        s2.w = fmaf(acc.w, acc.w, s2.w);
    }
    red[t] = s;
    for (int hh = RPB / 2; hh > 0; hh >>= 1) {
        __syncthreads();
        if (r0 < hh) red[t] = f4add(red[t], red[t + hh * CG]);
    }
    if (r0 == 0) {
        float4 a = red[t];
        atomicAdd(&sums4[c0 + 0], a.x); atomicAdd(&sums4[c0 + 1], a.y);
        atomicAdd(&sums4[c0 + 2], a.z); atomicAdd(&sums4[c0 + 3], a.w);
    }
    __syncthreads();
    red[t] = s2;
    for (int hh = RPB / 2; hh > 0; hh >>= 1) {
        __syncthreads();
        if (r0 < hh) red[t] = f4add(red[t], red[t + hh * CG]);
    }
    if (r0 == 0) {
        float4 b = red[t];
        atomicAdd(&sumsq4[c0 + 0], b.x); atomicAdd(&sumsq4[c0 + 1], b.y);
        atomicAdd(&sumsq4[c0 + 2], b.z); atomicAdd(&sumsq4[c0 + 3], b.w);
    }
}

// ---------------- head: BN4+ReLU on load, FC2, row-L2-normalize ----------------

__global__ void k_head(const float* __restrict__ Z, const float* __restrict__ sums,
                       const float* __restrict__ sumsq, const float* __restrict__ gam,
                       const float* __restrict__ bet, const float* __restrict__ Wf2,
                       const float* __restrict__ bf2, float* __restrict__ out) {
    int g = blockIdx.x, c = threadIdx.x;  // 64 threads = 1 wave
    __shared__ float row[128];
    const float invG = 1.0f / (float)NG;
    for (int j = c; j < 128; j += 64) {
        float sc, sh;
        bnparam(sums[j], sumsq[j], gam[j], bet[j], invG, sc, sh);
        row[j] = fmaxf(fmaf(sc, Z[(g << 7) + j], sh), 0.f);
    }
    __syncthreads();
    float acc = bf2[c];
#pragma unroll
    for (int k = 0; k < 128; ++k) acc = fmaf(row[k], Wf2[k * 64 + c], acc);
    float ss = acc * acc;
#pragma unroll
    for (int off = 32; off; off >>= 1) ss += __shfl_xor(ss, off);
    out[(g << 6) + c] = acc / fmaxf(sqrtf(ss), 1e-12f);
}

// ---------------- launch ----------------

extern "C" void kernel_launch(void* const* d_in, const int* in_sizes, int n_in,
                              void* d_out, int out_size, void* d_ws, size_t ws_size,
                              hipStream_t stream) {
    const float* x    = (const float*)d_in[0];
    const int*   src  = (const int*)d_in[1];
    const int*   dst  = (const int*)d_in[2];
    const int*   batch= (const int*)d_in[3];
    const float* W1   = (const float*)d_in[4];   // b1 cancels in BN
    const float* g1   = (const float*)d_in[6];
    const float* be1  = (const float*)d_in[7];
    const float* W2   = (const float*)d_in[8];   // b2 cancels
    const float* g2   = (const float*)d_in[10];
    const float* be2  = (const float*)d_in[11];
    const float* W3   = (const float*)d_in[12];  // b3 cancels
    const float* g3   = (const float*)d_in[14];
    const float* be3  = (const float*)d_in[15];
    const float* Wf1  = (const float*)d_in[16];  // bf1 cancels
    const float* g4   = (const float*)d_in[18];
    const float* be4  = (const float*)d_in[19];
    const float* Wf2  = (const float*)d_in[20];
    const float* bf2  = (const float*)d_in[21];
    float* out = (float*)d_out;

    const int N = in_sizes[0] / 6;
    const int E = in_sizes[1];
    const int nScanBlocks = (N + SCAN_T * SCAN_I - 1) / (SCAN_T * SCAN_I);

    // workspace carve-up
    char* ws = (char*)d_ws;
    size_t off = 0;
    auto carve = [&](size_t bytes) {
        void* p = ws + off;
        off += (bytes + 255) & ~(size_t)255;
        return p;
    };
    int*    cnt    = (int*)carve((size_t)N * 4);
    float*  dinv   = (float*)carve((size_t)N * 4);
    int*    rowptr = (int*)carve((size_t)N * 4);
    int*    fill   = (int*)carve((size_t)N * 4);
    int*    bsum   = (int*)carve((size_t)4096 * 4);
    int*    esrc   = (int*)carve((size_t)E * 4);
    float*  ewt    = (float*)carve((size_t)E * 4);
    __half* H1     = (__half*)carve((size_t)N * 32 * 2);  // fp16 layer-1 output
    __half* H2     = (__half*)carve((size_t)N * 64 * 2);  // fp16 layer-2 output
    float*  stats  = (float*)carve(704 * 4);
    int*    pool   = (int*)carve((size_t)NG * 128 * 4);   // monotone-int max keys
    float*  Z      = (float*)carve((size_t)NG * 128 * 4);
    float* s1 = stats;        // L1 sums/sumsq (32+32)
    float* s2 = stats + 64;   // L2 (64+64)
    float* s3 = stats + 192;  // L3 (128+128)
    float* s4 = stats + 448;  // head (128+128)

    const float invN = 1.0f / (float)N;

    // ---- build dst-sorted CSR (once; reused by all 3 layers) ----
    hipMemsetAsync(cnt, 0, (size_t)N * 4, stream);
    hipMemsetAsync(fill, 0, (size_t)N * 4, stream);
    hipMemsetAsync(stats, 0, 704 * 4, stream);
    hipMemsetAsync(pool, 0x80, (size_t)NG * 128 * 4, stream);  // ~key(-FLT_MAX)
    k_count<<<(E + 255) / 256, 256, 0, stream>>>(dst, cnt, E);
    k_dinv<<<(N + 255) / 256, 256, 0, stream>>>(cnt, dinv, N);
    k_scan1<<<nScanBlocks, SCAN_T, 0, stream>>>(cnt, rowptr, bsum, N);
    k_scan2<<<1, SCAN_T, 0, stream>>>(bsum, nScanBlocks);
    k_scan3<<<nScanBlocks, SCAN_T, 0, stream>>>(rowptr, bsum, N);
    k_bucket<<<(E + 255) / 256, 256, 0, stream>>>(src, dst, dinv, rowptr, fill, esrc, ewt, E);

    // ---- layer 1 fused: gather x (C=6) + mm 6->32 + stats1 -> H1 (fp16) ----
    k_layer1<32><<<(N + 255) / 256, 256, 0, stream>>>(
        rowptr, cnt, esrc, ewt, dinv, x, W1, H1, s1, s1 + 32, N);

    // ---- layer 2 fused: fp16 gather bnrelu1(H1) + mm 32->64 + stats2 -> H2 (fp16) ----
    k_layerF<32, 64, 64, false><<<(N + 63) / 64, 256, 0, stream>>>(
        rowptr, cnt, esrc, ewt, dinv, H1, s1, s1 + 32, g1, be1, W2, H2,
        s2, s2 + 64, nullptr, nullptr, N, invN);

    // ---- layer 3 fused: fp16 gather bnrelu2(H2) + mm 64->128 + stats3 + raw segmax -> pool ----
    k_layerF<64, 128, 64, true><<<(N + 63) / 64, 256, 0, stream>>>(
        rowptr, cnt, esrc, ewt, dinv, H2, s2, s2 + 64, g2, be2, W3, nullptr,
        s3, s3 + 128, batch, pool, N, invN);

    // ---- head: decode pool + BN3 + ReLU + FC1 (+stats4), then BN4+ReLU+FC2+normalize ----
    k_mm_pool<<<NG / 64, 256, 0, stream>>>(
        pool, Wf1, s3, s3 + 128, g3, be3, Z, s4, s4 + 128, invN);
    k_head<<<NG, 64, 0, stream>>>(Z, s4, s4 + 128, g4, be4, Wf2, bf2, out);
}